// Round 2
// baseline (131.255 us; speedup 1.0000x reference)
//
#include <hip/hip_runtime.h>

// Overlapped-chunk HMM forward filter.
// Each 16-lane group owns CHUNK_L timesteps, warm-starts WARMUP_W steps early
// from the stationary distribution pi; exponential forgetting of the filter
// (Dobrushin contraction of P) makes the chunk boundary error ~0 by write time.
#define CHUNK_L 64
#define WARMUP_W 96

__global__ __launch_bounds__(256) void hmm_filter_kernel(
    const float* __restrict__ y,
    const float* __restrict__ logits,
    const float* __restrict__ mu,
    const float* __restrict__ log_sigma,
    float* __restrict__ out,
    int T)
{
    __shared__ float Plds[256];                 // P row-major
    __shared__ float Ba[256];                   // squaring buffer A
    __shared__ float Bb[256];                   // squaring buffer B
    __shared__ __align__(16) float vlds[256];   // per-group filtered state (16 floats each)

    const int tid = (int)threadIdx.x;
    const int j   = tid & 15;     // state / column index
    const int g   = tid >> 4;     // row index (preamble) / group id (main)

    // ---- P = softmax(logits, axis=-1); thread (row=g, col=j) ----
    float l = logits[tid];
    float m = l;
    #pragma unroll
    for (int s = 1; s < 16; s <<= 1) m = fmaxf(m, __shfl_xor(m, s, 16));
    float e = __expf(l - m);
    float rs = e;
    #pragma unroll
    for (int s = 1; s < 16; s <<= 1) rs += __shfl_xor(rs, s, 16);
    float Pv = e / rs;
    Plds[tid] = Pv;
    Ba[tid]   = Pv;
    __syncthreads();

    // ---- stationary pi: P^(2^10) via renormalized squaring ----
    float* cur = Ba;
    float* nxt = Bb;
    for (int itq = 0; itq < 10; ++itq) {
        float acc = 0.f;
        #pragma unroll
        for (int k = 0; k < 16; ++k)
            acc += cur[g * 16 + k] * cur[k * 16 + j];
        float rsum = acc;
        #pragma unroll
        for (int s = 1; s < 16; s <<= 1) rsum += __shfl_xor(rsum, s, 16);
        nxt[tid] = acc / rsum;
        __syncthreads();
        float* tmp = cur; cur = nxt; nxt = tmp;
    }
    // pi = any row of cur (converged); init each group's state with pi
    vlds[tid] = cur[j];

    // ---- P column j into registers: ut_j = sum_i v_i * P[i][j] ----
    float pc[16];
    #pragma unroll
    for (int k = 0; k < 16; ++k) pc[k] = Plds[k * 16 + j];
    __syncthreads();

    // emission constants for state j
    const float muj = mu[j];
    const float isj = __expf(-log_sigma[j]);          // 1/sigma_j
    const float cfj = 0.3989422804014327f * isj;      // 1/(sigma*sqrt(2pi))

    const long long c     = (long long)blockIdx.x * 16 + g;  // chunk id
    const long long wfrom = c * (long long)CHUNK_L;          // first written t
    if (wfrom >= (long long)T) return;                       // dead chunk (no barriers below)
    long long end = wfrom + CHUNK_L;
    if (end > (long long)T) end = (long long)T;
    long long start = wfrom - WARMUP_W;
    if (start < 0) start = 0;   // clamped chunks run the EXACT filter from t=0

    float* __restrict__ outUt = out;
    float* __restrict__ outUn = out + (long long)T * 16;
    float* __restrict__ outFt = out + (long long)T * 32;

    const int vb = g * 16;

    // one filter step at time t
    auto step = [&](long long t, float& o_ut, float& o_utt, float& o_f) {
        const float4 v0 = *(const float4*)&vlds[vb + 0];
        const float4 v1 = *(const float4*)&vlds[vb + 4];
        const float4 v2 = *(const float4*)&vlds[vb + 8];
        const float4 v3 = *(const float4*)&vlds[vb + 12];
        float a0 = fmaf(v0.x, pc[0],  fmaf(v0.y, pc[1],  fmaf(v0.z, pc[2],  v0.w * pc[3])));
        float a1 = fmaf(v1.x, pc[4],  fmaf(v1.y, pc[5],  fmaf(v1.z, pc[6],  v1.w * pc[7])));
        float a2 = fmaf(v2.x, pc[8],  fmaf(v2.y, pc[9],  fmaf(v2.z, pc[10], v2.w * pc[11])));
        float a3 = fmaf(v3.x, pc[12], fmaf(v3.y, pc[13], fmaf(v3.z, pc[14], v3.w * pc[15])));
        float ut = (a0 + a1) + (a2 + a3);              // (v @ P)_j
        const float yt = y[t];
        const float z  = (yt - muj) * isj;
        const float gj = __expf(-0.5f * z * z) * cfj;  // N(y_t; mu_j, sigma_j^2)
        const float p  = ut * gj;
        float f = p;
        #pragma unroll
        for (int s = 1; s < 16; s <<= 1) f += __shfl_xor(f, s, 16);
        const float inv = __builtin_amdgcn_rcpf(f);
        const float utt = p * inv;
        vlds[vb + j] = utt;
        // compiler fence: next iteration's vector read must not hoist past this
        // scalar write (HW DS pipe is in-order per wave; only the compiler can reorder)
        __asm__ __volatile__("" ::: "memory");
        o_ut = ut; o_utt = utt; o_f = f;
    };

    // warm-up (no writes)
    float d0, d1, d2;
    for (long long t = start; t < wfrom; ++t)
        step(t, d0, d1, d2);

    // main chunk: write outputs
    for (long long t = wfrom; t < end; ++t) {
        float utv, uttv, fv;
        step(t, utv, uttv, fv);
        const long long r = t * 16 + j;
        outUt[r] = utv;
        outUn[r] = uttv;
        if (j == 0) outFt[t] = fv;
    }
}

extern "C" void kernel_launch(void* const* d_in, const int* in_sizes, int n_in,
                              void* d_out, int out_size, void* d_ws, size_t ws_size,
                              hipStream_t stream) {
    const float* y      = (const float*)d_in[0];
    const float* logits = (const float*)d_in[1];
    const float* mu     = (const float*)d_in[2];
    const float* ls     = (const float*)d_in[3];
    float* out = (float*)d_out;
    const int T = in_sizes[0];

    const long long nchunks = ((long long)T + CHUNK_L - 1) / CHUNK_L;
    const int blocks = (int)((nchunks + 15) / 16);
    hmm_filter_kernel<<<blocks, 256, 0, stream>>>(y, logits, mu, ls, out, T);
}

// Round 3
// 106.950 us; speedup vs baseline: 1.2273x; 1.2273x over previous
//
#include <hip/hip_runtime.h>

// Overlapped-chunk HMM forward filter, all-VALU inner loop.
// Each 16-lane group owns CHUNK_L timesteps, warm-starts WARMUP_W steps early
// from the stationary distribution pi (filter contraction kills the init error).
// State alpha_j lives in a register of lane j; the 16-way matvec broadcast uses
// DPP row_newbcast (rows of 16 == groups), the normalizer uses a DPP ring
// reduction (row_ror 1,2,4,8). Zero LDS/DS ops in the hot loop.
#define CHUNK_L 32
#define WARMUP_W 48

// DPP helpers (ctrl must be a literal at each use site)
#define DPPI(src_i, ctrl) __builtin_amdgcn_update_dpp(0, (src_i), (ctrl), 0xF, 0xF, true)

__global__ __launch_bounds__(256) void hmm_filter_kernel(
    const float* __restrict__ y,
    const float* __restrict__ logits,
    const float* __restrict__ mu,
    const float* __restrict__ log_sigma,
    float* __restrict__ out,
    int T)
{
    __shared__ float Plds[256];   // P row-major
    __shared__ float Ba[256];     // squaring buffer A
    __shared__ float Bb[256];     // squaring buffer B

    const int tid = (int)threadIdx.x;
    const int j   = tid & 15;     // state / column index
    const int g   = tid >> 4;     // row index (preamble) / group id (main)

    // ---- P = softmax(logits, axis=-1); thread (row=g, col=j) ----
    float l = logits[tid];
    float m = l;
    #pragma unroll
    for (int s = 1; s < 16; s <<= 1) m = fmaxf(m, __shfl_xor(m, s, 16));
    float e = __expf(l - m);
    float rs = e;
    #pragma unroll
    for (int s = 1; s < 16; s <<= 1) rs += __shfl_xor(rs, s, 16);
    float Pv = e / rs;
    Plds[tid] = Pv;
    Ba[tid]   = Pv;
    __syncthreads();

    // ---- stationary pi: P^(2^10) via renormalized squaring (amortized, cold) ----
    float* cur = Ba;
    float* nxt = Bb;
    for (int itq = 0; itq < 10; ++itq) {
        float acc = 0.f;
        #pragma unroll
        for (int k = 0; k < 16; ++k)
            acc += cur[g * 16 + k] * cur[k * 16 + j];
        float rsum = acc;
        #pragma unroll
        for (int s = 1; s < 16; s <<= 1) rsum += __shfl_xor(rsum, s, 16);
        nxt[tid] = acc / rsum;
        __syncthreads();
        float* tmp = cur; cur = nxt; nxt = tmp;
    }
    // last loop iteration ended with __syncthreads(); reads below are safe,
    // and there are no barriers after this point (early return below is OK).

    // state init: alpha_j = pi_j
    float a = cur[j];

    // P column j into registers: up_j = sum_i alpha_i * P[i][j]
    float pc[16];
    #pragma unroll
    for (int k = 0; k < 16; ++k) pc[k] = Plds[k * 16 + j];

    // emission constants for state j
    const float muj = mu[j];
    const float isj = __expf(-log_sigma[j]);          // 1/sigma_j
    const float cfj = 0.3989422804014327f * isj;      // 1/(sigma*sqrt(2pi))
    const float nmj = -muj * isj;                     // z = fmaf(y, isj, nmj)

    const long long c     = (long long)blockIdx.x * 16 + g;  // chunk id
    const long long wfrom = c * (long long)CHUNK_L;          // first written t
    if (wfrom >= (long long)T) return;                       // dead chunk
    long long end = wfrom + CHUNK_L;
    if (end > (long long)T) end = (long long)T;
    long long start = wfrom - WARMUP_W;
    if (start < 0) start = 0;   // clamped chunks run the EXACT filter from t=0

    float* __restrict__ outUt = out;
    float* __restrict__ outUn = out + (long long)T * 16;
    float* __restrict__ outFt = out + (long long)T * 32;

    // one filter step; pure VALU. emit is a compile-time-foldable literal.
    auto step = [&](float av, float yt, bool emit, long long t) -> float {
        const int ai = __float_as_int(av);
        float u0 =      __int_as_float(DPPI(ai, 0x150)) * pc[0];
        float u1 =      __int_as_float(DPPI(ai, 0x151)) * pc[1];
        float u2 =      __int_as_float(DPPI(ai, 0x152)) * pc[2];
        float u3 =      __int_as_float(DPPI(ai, 0x153)) * pc[3];
        u0 = fmaf(__int_as_float(DPPI(ai, 0x154)), pc[4],  u0);
        u1 = fmaf(__int_as_float(DPPI(ai, 0x155)), pc[5],  u1);
        u2 = fmaf(__int_as_float(DPPI(ai, 0x156)), pc[6],  u2);
        u3 = fmaf(__int_as_float(DPPI(ai, 0x157)), pc[7],  u3);
        u0 = fmaf(__int_as_float(DPPI(ai, 0x158)), pc[8],  u0);
        u1 = fmaf(__int_as_float(DPPI(ai, 0x159)), pc[9],  u1);
        u2 = fmaf(__int_as_float(DPPI(ai, 0x15A)), pc[10], u2);
        u3 = fmaf(__int_as_float(DPPI(ai, 0x15B)), pc[11], u3);
        u0 = fmaf(__int_as_float(DPPI(ai, 0x15C)), pc[12], u0);
        u1 = fmaf(__int_as_float(DPPI(ai, 0x15D)), pc[13], u1);
        u2 = fmaf(__int_as_float(DPPI(ai, 0x15E)), pc[14], u2);
        u3 = fmaf(__int_as_float(DPPI(ai, 0x15F)), pc[15], u3);
        float up = (u0 + u1) + (u2 + u3);              // (alpha @ P)_j

        float z  = fmaf(yt, isj, nmj);
        float gj = __expf(-0.5f * z * z) * cfj;        // N(y_t; mu_j, sigma_j^2)
        float p  = up * gj;

        // ring all-reduce within the 16-lane row: every lane gets sum(p)
        float s = p;
        s += __int_as_float(DPPI(__float_as_int(s), 0x121));  // row_ror:1
        s += __int_as_float(DPPI(__float_as_int(s), 0x122));  // row_ror:2
        s += __int_as_float(DPPI(__float_as_int(s), 0x124));  // row_ror:4
        s += __int_as_float(DPPI(__float_as_int(s), 0x128));  // row_ror:8

        float r  = __builtin_amdgcn_rcpf(s);
        float an = p * r;                              // normalized posterior
        if (emit) {
            const long long ri = t * 16 + j;
            outUt[ri] = up;
            outUn[ri] = an;
            if (j == 0) outFt[t] = s;
        }
        return an;
    };

    long long t = start;
    // warm-up (no writes); trip counts here are multiples of 4, starts mult of 16
    for (; t + 4 <= wfrom; t += 4) {
        const float4 y4 = *(const float4*)(y + t);
        a = step(a, y4.x, false, t);
        a = step(a, y4.y, false, t + 1);
        a = step(a, y4.z, false, t + 2);
        a = step(a, y4.w, false, t + 3);
    }
    for (; t < wfrom; ++t) a = step(a, y[t], false, t);

    // main chunk: write outputs
    for (; t + 4 <= end; t += 4) {
        const float4 y4 = *(const float4*)(y + t);
        a = step(a, y4.x, true, t);
        a = step(a, y4.y, true, t + 1);
        a = step(a, y4.z, true, t + 2);
        a = step(a, y4.w, true, t + 3);
    }
    for (; t < end; ++t) a = step(a, y[t], true, t);
}

extern "C" void kernel_launch(void* const* d_in, const int* in_sizes, int n_in,
                              void* d_out, int out_size, void* d_ws, size_t ws_size,
                              hipStream_t stream) {
    const float* y      = (const float*)d_in[0];
    const float* logits = (const float*)d_in[1];
    const float* mu     = (const float*)d_in[2];
    const float* ls     = (const float*)d_in[3];
    float* out = (float*)d_out;
    const int T = in_sizes[0];

    const long long nchunks = ((long long)T + CHUNK_L - 1) / CHUNK_L;
    const int blocks = (int)((nchunks + 15) / 16);
    hmm_filter_kernel<<<blocks, 256, 0, stream>>>(y, logits, mu, ls, out, T);
}